// Round 2
// baseline (1017.265 us; speedup 1.0000x reference)
//
#include <hip/hip_runtime.h>
#include <hip/hip_bf16.h>
#include <math.h>

typedef __hip_bfloat16 bf16;

#define F_IN 64
#define PRE 32
#define KNB 6

// ws float offsets (fp32 weights + flags) — total ~52.3 KB, safe for any ws_size
#define WOFF_WP   0      // 2048
#define WOFF_BP   2048   // 32
#define WOFF_WE1  2080   // 6336
#define WOFF_BE1  8416   // 32
#define WOFF_WE2  8448   // 1024
#define WOFF_BE2  9472   // 32
#define WOFF_WE3  9504   // 192
#define WOFF_BE3  9696   // 6
#define WOFF_WS1  9728   // 2048
#define WOFF_BS1  11776  // 32
#define WOFF_WS2  11808  // 1024
#define WOFF_BS2  12832  // 32
#define WOFF_WS3  12864  // 32
#define WOFF_BS3  12896  // 1
#define FLAGS_OFF 13056  // int[2]: {is_bf16, is_int64}

__device__ __forceinline__ float b2f(bf16 v) { return __bfloat162float(v); }
__device__ __forceinline__ float eluf(float v) { return v > 0.f ? v : expm1f(v); }

__device__ __forceinline__ void bf8_to_f32(uint4 u, float* f) {
  unsigned int w[4] = {u.x, u.y, u.z, u.w};
#pragma unroll
  for (int i = 0; i < 4; i++) {
    f[2 * i]     = __uint_as_float(w[i] << 16);
    f[2 * i + 1] = __uint_as_float(w[i] & 0xffff0000u);
  }
}

// ---- dtype detection (device-side; no host sync allowed) ----
__global__ void detect(const ushort* xb, const int* ni, int* flags) {
  if (threadIdx.x == 0 && blockIdx.x == 0) {
    // bf16 test: true bf16 N(0,1) has |v| < ~7 for all elements.
    // fp32 reinterpreted as bf16 pairs -> low-half words are random bits:
    // ~47% have |v|>100 or NaN/inf.
    int bad = 0;
    for (int i = 0; i < 256; i++) {
      float v = __uint_as_float(((unsigned)xb[i]) << 16);
      if (!(fabsf(v) < 100.f)) bad++;   // NaN also lands here
    }
    // int64 test: int64 nidx in [0, 2^31) has all-zero high words.
    int hi_nonzero = 0;
    for (int i = 0; i < 64; i++) if (ni[2 * i + 1] != 0) hi_nonzero = 1;
    flags[0] = (bad < 8) ? 1 : 0;
    flags[1] = hi_nonzero ? 0 : 1;
  }
}

// ---- weight staging: any-float -> fp32 in ws ----
__global__ void wstage(const void* Wp, const void* bp, const void* We1, const void* be1,
                       const void* We2, const void* be2, const void* We3, const void* be3,
                       const void* Ws1, const void* bs1, const void* Ws2, const void* bs2,
                       const void* Ws3, const void* bs3, float* w, const int* flags) {
  const void* srcs[14] = {Wp, bp, We1, be1, We2, be2, We3, be3, Ws1, bs1, Ws2, bs2, Ws3, bs3};
  const int sizes[14] = {2048, 32, 6336, 32, 1024, 32, 192, 6, 2048, 32, 1024, 32, 32, 1};
  const int offs[14] = {WOFF_WP, WOFF_BP, WOFF_WE1, WOFF_BE1, WOFF_WE2, WOFF_BE2, WOFF_WE3,
                        WOFF_BE3, WOFF_WS1, WOFF_BS1, WOFF_WS2, WOFF_BS2, WOFF_WS3, WOFF_BS3};
  int bf = flags[0];
  int t = blockIdx.x;
  const void* s = srcs[t];
  int nel = sizes[t];
  float* d = w + offs[t];
  if (bf) {
    const bf16* sb = (const bf16*)s;
    for (int i = threadIdx.x; i < nel; i += blockDim.x) d[i] = b2f(sb[i]);
  } else {
    const float* sf = (const float*)s;
    for (int i = threadIdx.x; i < nel; i += blockDim.x) d[i] = sf[i];
  }
}

// ---- fused per-node forward ----
template <bool BF16>
__device__ __forceinline__ void load_row8(const void* base, long row, int chunk, float* f) {
  if (BF16) {
    const uint4* p = (const uint4*)((const ushort*)base + row * F_IN);
    bf8_to_f32(p[chunk], f);
  } else {
    const float4* p = (const float4*)((const float*)base + row * F_IN);
    float4 a = p[2 * chunk];
    float4 b = p[2 * chunk + 1];
    f[0] = a.x; f[1] = a.y; f[2] = a.z; f[3] = a.w;
    f[4] = b.x; f[5] = b.y; f[6] = b.z; f[7] = b.w;
  }
}

template <bool BF16>
__device__ void node_body(int n, int n_nodes, const void* xv, const void* dsv,
                          const int* __restrict__ ni, int i64,
                          const float* __restrict__ w, void* outv) {
  const float* Wp  = w + WOFF_WP;
  const float* bp  = w + WOFF_BP;
  const float* We1 = w + WOFF_WE1;
  const float* be1 = w + WOFF_BE1;
  const float* We2 = w + WOFF_WE2;
  const float* be2 = w + WOFF_BE2;
  const float* We3 = w + WOFF_WE3;
  const float* be3 = w + WOFF_BE3;
  const float* Ws1 = w + WOFF_WS1;
  const float* bs1 = w + WOFF_BS1;
  const float* Ws2 = w + WOFF_WS2;
  const float* bs2 = w + WOFF_BS2;
  const float* Ws3 = w + WOFF_WS3;
  const float* bs3 = w + WOFF_BS3;

  // own row: pre-dense h and self-layer-1 s1 streamed together
  float h[32], s1[32];
#pragma unroll
  for (int o = 0; o < 32; o++) { h[o] = bp[o]; s1[o] = bs1[o]; }
  for (int c = 0; c < 8; c++) {
    float xv8[8];
    load_row8<BF16>(xv, n, c, xv8);
#pragma unroll
    for (int q = 0; q < 8; q++) {
      int j = c * 8 + q;
      float xj = xv8[q];
#pragma unroll
      for (int o = 0; o < 32; o++) {
        h[o]  += xj * Wp[j * 32 + o];
        s1[o] += xj * Ws1[j * 32 + o];
      }
    }
  }

  float own[32];
#pragma unroll
  for (int o = 0; o < 32; o++) own[o] = eluf(h[o]);

  // self MLP tail
  float s2[32];
#pragma unroll
  for (int o = 0; o < 32; o++) s2[o] = bs2[o];
  for (int j = 0; j < 32; j++) {
    float v = eluf(s1[j]);
#pragma unroll
    for (int o = 0; o < 32; o++) s2[o] += v * Ws2[j * 32 + o];
  }
  float xs = bs3[0];
#pragma unroll
  for (int j = 0; j < 32; j++) xs += eluf(s2[j]) * Ws3[j];

  // edge layer 1: recompute neighbor pre-dense on the fly (no big scratch)
  float h1[32];
#pragma unroll
  for (int o = 0; o < 32; o++) h1[o] = be1[o];

  for (int k = 0; k < KNB; k++) {
    long pos = (long)n * KNB + k;
    int idx = i64 ? ni[2 * pos] : ni[pos];
    float m = idx < 0 ? 0.f : 1.f;
    long ai = idx < 0 ? 0 : idx;
    if (ai >= n_nodes) ai = 0;  // safety clamp

    float nh[32];
#pragma unroll
    for (int o = 0; o < 32; o++) nh[o] = bp[o];
    for (int c = 0; c < 8; c++) {
      float xv8[8];
      load_row8<BF16>(xv, ai, c, xv8);
#pragma unroll
      for (int q = 0; q < 8; q++) {
        int j = c * 8 + q;
        float xj = xv8[q];
#pragma unroll
        for (int o = 0; o < 32; o++) nh[o] += xj * Wp[j * 32 + o];
      }
    }

    const float* Wk = We1 + (k * 33) * 32;
#pragma unroll
    for (int j = 0; j < 32; j++) {
      float d = own[j] - m * eluf(nh[j]);
#pragma unroll
      for (int o = 0; o < 32; o++) h1[o] += d * Wk[j * 32 + o];
    }
    float dsq = BF16 ? b2f(((const bf16*)dsv)[pos]) : ((const float*)dsv)[pos];
#pragma unroll
    for (int o = 0; o < 32; o++) h1[o] += dsq * Wk[32 * 32 + o];
  }

  // edge layer 2
  float h2[32];
#pragma unroll
  for (int o = 0; o < 32; o++) h2[o] = be2[o];
  for (int j = 0; j < 32; j++) {
    float v = eluf(h1[j]);
#pragma unroll
    for (int o = 0; o < 32; o++) h2[o] += v * We2[j * 32 + o];
  }

  // edge layer 3 + self logit
  float lg[7];
  lg[0] = xs;
#pragma unroll
  for (int o = 0; o < 6; o++) lg[1 + o] = be3[o];
  for (int j = 0; j < 32; j++) {
    float v = eluf(h2[j]);
#pragma unroll
    for (int o = 0; o < 6; o++) lg[1 + o] += v * We3[j * 6 + o];
  }

  // softmax over 7
  float mx = lg[0];
#pragma unroll
  for (int i = 1; i < 7; i++) mx = fmaxf(mx, lg[i]);
  float e[7], ssum = 0.f;
#pragma unroll
  for (int i = 0; i < 7; i++) { e[i] = expf(lg[i] - mx); ssum += e[i]; }
  float inv = 1.f / ssum;
  if (BF16) {
    bf16* o = (bf16*)outv;
#pragma unroll
    for (int i = 0; i < 7; i++) o[(long)n * 7 + i] = __float2bfloat16(e[i] * inv);
  } else {
    float* o = (float*)outv;
#pragma unroll
    for (int i = 0; i < 7; i++) o[(long)n * 7 + i] = e[i] * inv;
  }
}

__launch_bounds__(256)
__global__ void fused(const void* xv, const void* dsv, const int* __restrict__ ni,
                      const float* __restrict__ w, const int* __restrict__ flags,
                      void* outv, int n_nodes) {
  int n = blockIdx.x * blockDim.x + threadIdx.x;
  if (n >= n_nodes) return;
  int bf = flags[0];
  int i64 = flags[1];
  if (bf) node_body<true>(n, n_nodes, xv, dsv, ni, i64, w, outv);
  else    node_body<false>(n, n_nodes, xv, dsv, ni, i64, w, outv);
}

extern "C" void kernel_launch(void* const* d_in, const int* in_sizes, int n_in,
                              void* d_out, int out_size, void* d_ws, size_t ws_size,
                              hipStream_t stream) {
  const void* x      = d_in[0];
  const void* distsq = d_in[1];
  const int*  nidx   = (const int*)d_in[2];

  float* w = (float*)d_ws;
  int* flags = (int*)(w + FLAGS_OFF);

  int n_nodes = in_sizes[0] / F_IN;

  detect<<<1, 64, 0, stream>>>((const ushort*)x, nidx, flags);
  wstage<<<14, 256, 0, stream>>>(d_in[3], d_in[4], d_in[5], d_in[6], d_in[7], d_in[8],
                                 d_in[9], d_in[10], d_in[11], d_in[12], d_in[13], d_in[14],
                                 d_in[15], d_in[16], w, flags);
  int grid = (n_nodes + 255) / 256;
  fused<<<grid, 256, 0, stream>>>(x, distsq, nidx, w, flags, d_out, n_nodes);
}

// Round 3
// 479.555 us; speedup vs baseline: 2.1213x; 2.1213x over previous
//
#include <hip/hip_runtime.h>
#include <hip/hip_bf16.h>
#include <math.h>

typedef __hip_bfloat16 bf16;

#define F_IN 64
#define PRE 32
#define KNB 6

// ws float offsets (fp32 weights + flags); staged xp/xs start at float 16384
#define WOFF_WP   0      // 2048
#define WOFF_BP   2048   // 32
#define WOFF_WE1  2080   // 6336
#define WOFF_BE1  8416   // 32
#define WOFF_WE2  8448   // 1024
#define WOFF_BE2  9472   // 32
#define WOFF_WE3  9504   // 192
#define WOFF_BE3  9696   // 6
#define WOFF_WS1  9728   // 2048
#define WOFF_BS1  11776  // 32
#define WOFF_WS2  11808  // 1024
#define WOFF_BS2  12832  // 32
#define WOFF_WS3  12864  // 32
#define WOFF_BS3  12896  // 1
#define FLAGS_OFF 13056  // int[2]: {is_bf16, is_int64}
#define STAGE_OFF 16384  // floats

__device__ __forceinline__ float b2f(bf16 v) { return __bfloat162float(v); }
__device__ __forceinline__ float eluf(float v) { return v > 0.f ? v : expm1f(v); }

__device__ __forceinline__ ushort f2bu(float v) {
  bf16 b = __float2bfloat16(v);
  ushort u;
  __builtin_memcpy(&u, &b, 2);
  return u;
}

__device__ __forceinline__ void bf8_to_f32(uint4 u, float* f) {
  unsigned int w[4] = {u.x, u.y, u.z, u.w};
#pragma unroll
  for (int i = 0; i < 4; i++) {
    f[2 * i]     = __uint_as_float(w[i] << 16);
    f[2 * i + 1] = __uint_as_float(w[i] & 0xffff0000u);
  }
}

// ---- dtype detection (device-side; no host sync allowed) ----
__global__ void detect(const ushort* xb, const int* ni, int* flags) {
  if (threadIdx.x == 0 && blockIdx.x == 0) {
    int bad = 0;
    for (int i = 0; i < 256; i++) {
      float v = __uint_as_float(((unsigned)xb[i]) << 16);
      if (!(fabsf(v) < 100.f)) bad++;
    }
    int hi_nonzero = 0;
    for (int i = 0; i < 64; i++) if (ni[2 * i + 1] != 0) hi_nonzero = 1;
    flags[0] = (bad < 8) ? 1 : 0;
    flags[1] = hi_nonzero ? 0 : 1;
  }
}

// ---- weight staging: any-float -> fp32 in ws ----
__global__ void wstage(const void* Wp, const void* bp, const void* We1, const void* be1,
                       const void* We2, const void* be2, const void* We3, const void* be3,
                       const void* Ws1, const void* bs1, const void* Ws2, const void* bs2,
                       const void* Ws3, const void* bs3, float* w, const int* flags) {
  const void* srcs[14] = {Wp, bp, We1, be1, We2, be2, We3, be3, Ws1, bs1, Ws2, bs2, Ws3, bs3};
  const int sizes[14] = {2048, 32, 6336, 32, 1024, 32, 192, 6, 2048, 32, 1024, 32, 32, 1};
  const int offs[14] = {WOFF_WP, WOFF_BP, WOFF_WE1, WOFF_BE1, WOFF_WE2, WOFF_BE2, WOFF_WE3,
                        WOFF_BE3, WOFF_WS1, WOFF_BS1, WOFF_WS2, WOFF_BS2, WOFF_WS3, WOFF_BS3};
  int bf = flags[0];
  int t = blockIdx.x;
  const void* s = srcs[t];
  int nel = sizes[t];
  float* d = w + offs[t];
  if (bf) {
    const bf16* sb = (const bf16*)s;
    for (int i = threadIdx.x; i < nel; i += blockDim.x) d[i] = b2f(sb[i]);
  } else {
    const float* sf = (const float*)s;
    for (int i = threadIdx.x; i < nel; i += blockDim.x) d[i] = sf[i];
  }
}

template <bool BF16>
__device__ __forceinline__ void load_row8(const void* base, long row, int chunk, float* f) {
  if (BF16) {
    const uint4* p = (const uint4*)((const ushort*)base + row * F_IN);
    bf8_to_f32(p[chunk], f);
  } else {
    const float4* p = (const float4*)((const float*)base + row * F_IN);
    float4 a = p[2 * chunk];
    float4 b = p[2 * chunk + 1];
    f[0] = a.x; f[1] = a.y; f[2] = a.z; f[3] = a.w;
    f[4] = b.x; f[5] = b.y; f[6] = b.z; f[7] = b.w;
  }
}

// ==================== staged path ====================

// A: pre-dense + self MLP. xp stored post-ELU as bf16 (64B/row), xs fp32.
template <bool BF16>
__device__ void pre_body(int n, const void* xv, const float* __restrict__ w,
                         ushort* __restrict__ xp, float* __restrict__ xs) {
  const float* Wp  = w + WOFF_WP;
  const float* bp  = w + WOFF_BP;
  const float* Ws1 = w + WOFF_WS1;
  const float* bs1 = w + WOFF_BS1;
  const float* Ws2 = w + WOFF_WS2;
  const float* bs2 = w + WOFF_BS2;
  const float* Ws3 = w + WOFF_WS3;
  const float* bs3 = w + WOFF_BS3;

  float h[32], s1[32];
#pragma unroll
  for (int o = 0; o < 32; o++) { h[o] = bp[o]; s1[o] = bs1[o]; }
  for (int c = 0; c < 8; c++) {
    float xv8[8];
    load_row8<BF16>(xv, n, c, xv8);
#pragma unroll
    for (int q = 0; q < 8; q++) {
      int j = c * 8 + q;
      float xj = xv8[q];
#pragma unroll
      for (int o = 0; o < 32; o++) {
        h[o]  += xj * Wp[j * 32 + o];
        s1[o] += xj * Ws1[j * 32 + o];
      }
    }
  }

  // store elu(h) as bf16 row
  uint4* xpo = (uint4*)(xp + (long)n * 32);
#pragma unroll
  for (int c = 0; c < 4; c++) {
    uint4 v;
    unsigned* vv = (unsigned*)&v;
#pragma unroll
    for (int i = 0; i < 4; i++) {
      float a = eluf(h[c * 8 + 2 * i]);
      float b = eluf(h[c * 8 + 2 * i + 1]);
      vv[i] = ((unsigned)f2bu(b) << 16) | (unsigned)f2bu(a);
    }
    xpo[c] = v;
  }

  float s2[32];
#pragma unroll
  for (int o = 0; o < 32; o++) s2[o] = bs2[o];
  for (int j = 0; j < 32; j++) {
    float v = eluf(s1[j]);
#pragma unroll
    for (int o = 0; o < 32; o++) s2[o] += v * Ws2[j * 32 + o];
  }
  float acc = bs3[0];
#pragma unroll
  for (int j = 0; j < 32; j++) acc += eluf(s2[j]) * Ws3[j];
  xs[n] = acc;
}

__launch_bounds__(256)
__global__ void node_pre(const void* xv, const float* __restrict__ w,
                         const int* __restrict__ flags,
                         ushort* __restrict__ xp, float* __restrict__ xs, int n_nodes) {
  int n = blockIdx.x * blockDim.x + threadIdx.x;
  if (n >= n_nodes) return;
  if (flags[0]) pre_body<true>(n, xv, w, xp, xs);
  else          pre_body<false>(n, xv, w, xp, xs);
}

// B: edge MLP from staged xp + softmax
template <bool BF16>
__device__ void edge_body(int n, int n_nodes, const ushort* __restrict__ xp,
                          const float* __restrict__ xs, const void* dsv,
                          const int* __restrict__ ni, int i64,
                          const float* __restrict__ w, void* outv) {
  const float* We1 = w + WOFF_WE1;
  const float* be1 = w + WOFF_BE1;
  const float* We2 = w + WOFF_WE2;
  const float* be2 = w + WOFF_BE2;
  const float* We3 = w + WOFF_WE3;
  const float* be3 = w + WOFF_BE3;

  // all neighbor indices first (independent loads in flight)
  int idxs[KNB];
#pragma unroll
  for (int k = 0; k < KNB; k++) {
    long pos = (long)n * KNB + k;
    idxs[k] = i64 ? ni[2 * pos] : ni[pos];
  }

  // own row
  const uint4* orow = (const uint4*)(xp + (long)n * 32);
  float own[32];
  {
    uint4 o0 = orow[0], o1 = orow[1], o2 = orow[2], o3 = orow[3];
    bf8_to_f32(o0, own + 0);
    bf8_to_f32(o1, own + 8);
    bf8_to_f32(o2, own + 16);
    bf8_to_f32(o3, own + 24);
  }

  float h1[32];
#pragma unroll
  for (int o = 0; o < 32; o++) h1[o] = be1[o];

  // depth-1 pipelined neighbor rows
  long a0 = (idxs[0] < 0 || idxs[0] >= n_nodes) ? 0 : idxs[0];
  const uint4* rp = (const uint4*)(xp + a0 * 32);
  uint4 rb0 = rp[0], rb1 = rp[1], rb2 = rp[2], rb3 = rp[3];

#pragma unroll
  for (int k = 0; k < KNB; k++) {
    uint4 nb0, nb1, nb2, nb3;
    if (k + 1 < KNB) {
      int ix = idxs[k + 1];
      long ai = (ix < 0 || ix >= n_nodes) ? 0 : ix;
      const uint4* np_ = (const uint4*)(xp + ai * 32);
      nb0 = np_[0]; nb1 = np_[1]; nb2 = np_[2]; nb3 = np_[3];
    }
    float m = idxs[k] < 0 ? 0.f : 1.f;
    const float* Wk = We1 + (k * 33) * 32;
    uint4 cur[4] = {rb0, rb1, rb2, rb3};
#pragma unroll
    for (int c = 0; c < 4; c++) {
      float nbv[8];
      bf8_to_f32(cur[c], nbv);
#pragma unroll
      for (int q = 0; q < 8; q++) {
        int j = c * 8 + q;
        float d = own[j] - m * nbv[q];
#pragma unroll
        for (int o = 0; o < 32; o++) h1[o] += d * Wk[j * 32 + o];
      }
    }
    long pos = (long)n * KNB + k;
    float dsq = BF16 ? b2f(((const bf16*)dsv)[pos]) : ((const float*)dsv)[pos];
#pragma unroll
    for (int o = 0; o < 32; o++) h1[o] += dsq * Wk[32 * 32 + o];
    if (k + 1 < KNB) { rb0 = nb0; rb1 = nb1; rb2 = nb2; rb3 = nb3; }
  }

  float h2[32];
#pragma unroll
  for (int o = 0; o < 32; o++) h2[o] = be2[o];
  for (int j = 0; j < 32; j++) {
    float v = eluf(h1[j]);
#pragma unroll
    for (int o = 0; o < 32; o++) h2[o] += v * We2[j * 32 + o];
  }

  float lg[7];
  lg[0] = xs[n];
#pragma unroll
  for (int o = 0; o < 6; o++) lg[1 + o] = be3[o];
  for (int j = 0; j < 32; j++) {
    float v = eluf(h2[j]);
#pragma unroll
    for (int o = 0; o < 6; o++) lg[1 + o] += v * We3[j * 6 + o];
  }

  float mx = lg[0];
#pragma unroll
  for (int i = 1; i < 7; i++) mx = fmaxf(mx, lg[i]);
  float e[7], ssum = 0.f;
#pragma unroll
  for (int i = 0; i < 7; i++) { e[i] = expf(lg[i] - mx); ssum += e[i]; }
  float inv = 1.f / ssum;
  if (BF16) {
    bf16* o = (bf16*)outv;
#pragma unroll
    for (int i = 0; i < 7; i++) o[(long)n * 7 + i] = __float2bfloat16(e[i] * inv);
  } else {
    float* o = (float*)outv;
#pragma unroll
    for (int i = 0; i < 7; i++) o[(long)n * 7 + i] = e[i] * inv;
  }
}

__launch_bounds__(256)
__global__ void edge(const ushort* __restrict__ xp, const float* __restrict__ xs,
                     const void* dsv, const int* __restrict__ ni,
                     const float* __restrict__ w, const int* __restrict__ flags,
                     void* outv, int n_nodes) {
  int n = blockIdx.x * blockDim.x + threadIdx.x;
  if (n >= n_nodes) return;
  int bf = flags[0];
  int i64 = flags[1];
  if (bf) edge_body<true>(n, n_nodes, xp, xs, dsv, ni, i64, w, outv);
  else    edge_body<false>(n, n_nodes, xp, xs, dsv, ni, i64, w, outv);
}

// ==================== fallback (proven round-2) path ====================

template <bool BF16>
__device__ void node_body(int n, int n_nodes, const void* xv, const void* dsv,
                          const int* __restrict__ ni, int i64,
                          const float* __restrict__ w, void* outv) {
  const float* Wp  = w + WOFF_WP;
  const float* bp  = w + WOFF_BP;
  const float* We1 = w + WOFF_WE1;
  const float* be1 = w + WOFF_BE1;
  const float* We2 = w + WOFF_WE2;
  const float* be2 = w + WOFF_BE2;
  const float* We3 = w + WOFF_WE3;
  const float* be3 = w + WOFF_BE3;
  const float* Ws1 = w + WOFF_WS1;
  const float* bs1 = w + WOFF_BS1;
  const float* Ws2 = w + WOFF_WS2;
  const float* bs2 = w + WOFF_BS2;
  const float* Ws3 = w + WOFF_WS3;
  const float* bs3 = w + WOFF_BS3;

  float h[32], s1[32];
#pragma unroll
  for (int o = 0; o < 32; o++) { h[o] = bp[o]; s1[o] = bs1[o]; }
  for (int c = 0; c < 8; c++) {
    float xv8[8];
    load_row8<BF16>(xv, n, c, xv8);
#pragma unroll
    for (int q = 0; q < 8; q++) {
      int j = c * 8 + q;
      float xj = xv8[q];
#pragma unroll
      for (int o = 0; o < 32; o++) {
        h[o]  += xj * Wp[j * 32 + o];
        s1[o] += xj * Ws1[j * 32 + o];
      }
    }
  }
  float own[32];
#pragma unroll
  for (int o = 0; o < 32; o++) own[o] = eluf(h[o]);
  float s2[32];
#pragma unroll
  for (int o = 0; o < 32; o++) s2[o] = bs2[o];
  for (int j = 0; j < 32; j++) {
    float v = eluf(s1[j]);
#pragma unroll
    for (int o = 0; o < 32; o++) s2[o] += v * Ws2[j * 32 + o];
  }
  float xs = bs3[0];
#pragma unroll
  for (int j = 0; j < 32; j++) xs += eluf(s2[j]) * Ws3[j];

  float h1[32];
#pragma unroll
  for (int o = 0; o < 32; o++) h1[o] = be1[o];
  for (int k = 0; k < KNB; k++) {
    long pos = (long)n * KNB + k;
    int idx = i64 ? ni[2 * pos] : ni[pos];
    float m = idx < 0 ? 0.f : 1.f;
    long ai = idx < 0 ? 0 : idx;
    if (ai >= n_nodes) ai = 0;
    float nh[32];
#pragma unroll
    for (int o = 0; o < 32; o++) nh[o] = bp[o];
    for (int c = 0; c < 8; c++) {
      float xv8[8];
      load_row8<BF16>(xv, ai, c, xv8);
#pragma unroll
      for (int q = 0; q < 8; q++) {
        int j = c * 8 + q;
        float xj = xv8[q];
#pragma unroll
        for (int o = 0; o < 32; o++) nh[o] += xj * Wp[j * 32 + o];
      }
    }
    const float* Wk = We1 + (k * 33) * 32;
#pragma unroll
    for (int j = 0; j < 32; j++) {
      float d = own[j] - m * eluf(nh[j]);
#pragma unroll
      for (int o = 0; o < 32; o++) h1[o] += d * Wk[j * 32 + o];
    }
    float dsq = BF16 ? b2f(((const bf16*)dsv)[pos]) : ((const float*)dsv)[pos];
#pragma unroll
    for (int o = 0; o < 32; o++) h1[o] += dsq * Wk[32 * 32 + o];
  }
  float h2[32];
#pragma unroll
  for (int o = 0; o < 32; o++) h2[o] = be2[o];
  for (int j = 0; j < 32; j++) {
    float v = eluf(h1[j]);
#pragma unroll
    for (int o = 0; o < 32; o++) h2[o] += v * We2[j * 32 + o];
  }
  float lg[7];
  lg[0] = xs;
#pragma unroll
  for (int o = 0; o < 6; o++) lg[1 + o] = be3[o];
  for (int j = 0; j < 32; j++) {
    float v = eluf(h2[j]);
#pragma unroll
    for (int o = 0; o < 6; o++) lg[1 + o] += v * We3[j * 6 + o];
  }
  float mx = lg[0];
#pragma unroll
  for (int i = 1; i < 7; i++) mx = fmaxf(mx, lg[i]);
  float e[7], ssum = 0.f;
#pragma unroll
  for (int i = 0; i < 7; i++) { e[i] = expf(lg[i] - mx); ssum += e[i]; }
  float inv = 1.f / ssum;
  if (BF16) {
    bf16* o = (bf16*)outv;
#pragma unroll
    for (int i = 0; i < 7; i++) o[(long)n * 7 + i] = __float2bfloat16(e[i] * inv);
  } else {
    float* o = (float*)outv;
#pragma unroll
    for (int i = 0; i < 7; i++) o[(long)n * 7 + i] = e[i] * inv;
  }
}

__launch_bounds__(256)
__global__ void fused(const void* xv, const void* dsv, const int* __restrict__ ni,
                      const float* __restrict__ w, const int* __restrict__ flags,
                      void* outv, int n_nodes) {
  int n = blockIdx.x * blockDim.x + threadIdx.x;
  if (n >= n_nodes) return;
  int bf = flags[0];
  int i64 = flags[1];
  if (bf) node_body<true>(n, n_nodes, xv, dsv, ni, i64, w, outv);
  else    node_body<false>(n, n_nodes, xv, dsv, ni, i64, w, outv);
}

extern "C" void kernel_launch(void* const* d_in, const int* in_sizes, int n_in,
                              void* d_out, int out_size, void* d_ws, size_t ws_size,
                              hipStream_t stream) {
  const void* x      = d_in[0];
  const void* distsq = d_in[1];
  const int*  nidx   = (const int*)d_in[2];

  float* w = (float*)d_ws;
  int* flags = (int*)(w + FLAGS_OFF);
  int n_nodes = in_sizes[0] / F_IN;

  detect<<<1, 64, 0, stream>>>((const ushort*)x, nidx, flags);
  wstage<<<14, 256, 0, stream>>>(d_in[3], d_in[4], d_in[5], d_in[6], d_in[7], d_in[8],
                                 d_in[9], d_in[10], d_in[11], d_in[12], d_in[13], d_in[14],
                                 d_in[15], d_in[16], w, flags);

  int grid = (n_nodes + 255) / 256;
  size_t need = (size_t)STAGE_OFF * 4 + (size_t)n_nodes * 32 * 2 + (size_t)n_nodes * 4 + 256;
  if (ws_size >= need) {
    ushort* xp = (ushort*)(w + STAGE_OFF);
    float* xs = (float*)(xp + (size_t)n_nodes * 32);
    node_pre<<<grid, 256, 0, stream>>>(x, w, flags, xp, xs, n_nodes);
    edge<<<grid, 256, 0, stream>>>(xp, xs, distsq, nidx, w, flags, d_out, n_nodes);
  } else {
    fused<<<grid, 256, 0, stream>>>(x, distsq, nidx, w, flags, d_out, n_nodes);
  }
}

// Round 4
// 298.897 us; speedup vs baseline: 3.4034x; 1.6044x over previous
//
#include <hip/hip_runtime.h>
#include <hip/hip_bf16.h>
#include <math.h>

typedef __hip_bfloat16 bf16;
typedef __attribute__((ext_vector_type(8))) __bf16 bf16x8;
typedef __attribute__((ext_vector_type(4))) float f32x4;

#define F_IN 64
#define KNB 6

// ws float offsets
#define WOFF_WP   0      // 2048
#define WOFF_BP   2048   // 32
#define WOFF_WE1  2080   // 6336
#define WOFF_BE1  8416   // 32
#define WOFF_WE2  8448   // 1024
#define WOFF_BE2  9472   // 32
#define WOFF_WE3  9504   // 192
#define WOFF_BE3  9696   // 6
#define WOFF_WS1  9728   // 2048
#define WOFF_BS1  11776  // 32
#define WOFF_WS2  11808  // 1024
#define WOFF_BS2  12832  // 32
#define WOFF_WS3  12864  // 32
#define WOFF_BS3  12896  // 1
#define FLAGS_OFF 13056  // int[2]
#define WOFF_WSUM 13312  // 1024  (sum_k We1 diff-block)
#define WOFF_WDSQ 14336  // 192   (dsq rows of We1, packed 6x32)
#define STAGE_OFF 16384  // floats; xp bf16 then xs fp32

__device__ __forceinline__ float b2f(bf16 v) { return __bfloat162float(v); }
__device__ __forceinline__ float eluf(float v) { return v > 0.f ? v : expm1f(v); }

__device__ __forceinline__ ushort f2bu(float v) {
  __bf16 b = (__bf16)v; ushort u; __builtin_memcpy(&u, &b, 2); return u;
}

union U8 { uint4 u; bf16x8 v; ushort s[8]; };

// wave-private LDS write->read fence: wait lgkmcnt(0) only (keep vmcnt in flight)
__device__ __forceinline__ void lds_fence() {
  __builtin_amdgcn_wave_barrier();
  __builtin_amdgcn_s_waitcnt(0xC07F);
  __builtin_amdgcn_wave_barrier();
}

// ---- dtype detection ----
__global__ void detect(const ushort* xb, const int* ni, int* flags) {
  if (threadIdx.x == 0 && blockIdx.x == 0) {
    int bad = 0;
    for (int i = 0; i < 256; i++) {
      float v = __uint_as_float(((unsigned)xb[i]) << 16);
      if (!(fabsf(v) < 100.f)) bad++;
    }
    int hi_nonzero = 0;
    for (int i = 0; i < 64; i++) if (ni[2 * i + 1] != 0) hi_nonzero = 1;
    flags[0] = (bad < 8) ? 1 : 0;
    flags[1] = hi_nonzero ? 0 : 1;
  }
}

// ---- weight staging to fp32 ----
__global__ void wstage(const void* Wp, const void* bp, const void* We1, const void* be1,
                       const void* We2, const void* be2, const void* We3, const void* be3,
                       const void* Ws1, const void* bs1, const void* Ws2, const void* bs2,
                       const void* Ws3, const void* bs3, float* w, const int* flags) {
  const void* srcs[14] = {Wp, bp, We1, be1, We2, be2, We3, be3, Ws1, bs1, Ws2, bs2, Ws3, bs3};
  const int sizes[14] = {2048, 32, 6336, 32, 1024, 32, 192, 6, 2048, 32, 1024, 32, 32, 1};
  const int offs[14] = {WOFF_WP, WOFF_BP, WOFF_WE1, WOFF_BE1, WOFF_WE2, WOFF_BE2, WOFF_WE3,
                        WOFF_BE3, WOFF_WS1, WOFF_BS1, WOFF_WS2, WOFF_BS2, WOFF_WS3, WOFF_BS3};
  int bf = flags[0];
  int t = blockIdx.x;
  const void* s = srcs[t];
  int nel = sizes[t];
  float* d = w + offs[t];
  if (bf) {
    const bf16* sb = (const bf16*)s;
    for (int i = threadIdx.x; i < nel; i += blockDim.x) d[i] = b2f(sb[i]);
  } else {
    const float* sf = (const float*)s;
    for (int i = threadIdx.x; i < nel; i += blockDim.x) d[i] = sf[i];
  }
}

// ---- derived weights: Wsum = sum_k We1 diff-block; Wdsq packed ----
__global__ void wprep(float* w) {
  int t = blockIdx.x * blockDim.x + threadIdx.x;
  if (t < 1024) {
    int j = t >> 5, o = t & 31;
    float s = 0.f;
    for (int k = 0; k < KNB; k++) s += w[WOFF_WE1 + (k * 33 + j) * 32 + o];
    w[WOFF_WSUM + t] = s;
  }
  if (t < 192) {
    int k = t >> 5, o = t & 31;
    w[WOFF_WDSQ + t] = w[WOFF_WE1 + (k * 33 + 32) * 32 + o];
  }
}

// B-fragment builder: lane(n=lane&15) holds B[k=quad*8+j][n] = sgn*W[k*ld + n]
__device__ __forceinline__ bf16x8 bfrag(const float* W, int ld, int nValid, int kValid, float sgn) {
  int lane = threadIdx.x & 63;
  int n = lane & 15, quad = lane >> 4;
  bf16x8 r;
#pragma unroll
  for (int j = 0; j < 8; j++) {
    int k = quad * 8 + j;
    float v = (n < nValid && k < kValid) ? sgn * W[k * ld + n] : 0.f;
    r[j] = (__bf16)v;
  }
  return r;
}

// A-fragment from a feature row (64 wide): lane(m=lane&15) holds row[k0+quad*8+j]
template <bool BF16>
__device__ __forceinline__ bf16x8 afrag_row(const void* base, long row, int k0) {
  int quad = (threadIdx.x & 63) >> 4;
  if (BF16) {
    U8 u;
    u.u = *(const uint4*)((const ushort*)base + row * F_IN + k0 + quad * 8);
    return u.v;
  } else {
    const float* p = (const float*)base + row * F_IN + k0 + quad * 8;
    float4 a = *(const float4*)p, b = *(const float4*)(p + 4);
    bf16x8 r;
    r[0] = (__bf16)a.x; r[1] = (__bf16)a.y; r[2] = (__bf16)a.z; r[3] = (__bf16)a.w;
    r[4] = (__bf16)b.x; r[5] = (__bf16)b.y; r[6] = (__bf16)b.z; r[7] = (__bf16)b.w;
    return r;
  }
}

// ==================== kernel A: pre-dense + self MLP (MFMA) ====================
template <bool BF16>
__device__ void pre_tiles(const void* xv, const float* __restrict__ w,
                          ushort* __restrict__ xp, float* __restrict__ xs,
                          int n_nodes, ushort* buf) {
  int lane = threadIdx.x & 63;
  int m = lane & 15, quad = lane >> 4;

  bf16x8 fwp[2][2], fws1[2][2], fws2[2], fws3;
#pragma unroll
  for (int s = 0; s < 2; s++)
#pragma unroll
    for (int t = 0; t < 2; t++) {
      fwp[s][t]  = bfrag(w + WOFF_WP  + s * 32 * 32 + 16 * t, 32, 16, 32, 1.f);
      fws1[s][t] = bfrag(w + WOFF_WS1 + s * 32 * 32 + 16 * t, 32, 16, 32, 1.f);
    }
#pragma unroll
  for (int t = 0; t < 2; t++) fws2[t] = bfrag(w + WOFF_WS2 + 16 * t, 32, 16, 32, 1.f);
  fws3 = bfrag(w + WOFF_WS3, 1, 1, 32, 1.f);
  float bpv[2], bs1v[2], bs2v[2];
#pragma unroll
  for (int t = 0; t < 2; t++) {
    bpv[t]  = w[WOFF_BP  + m + 16 * t];
    bs1v[t] = w[WOFF_BS1 + m + 16 * t];
    bs2v[t] = w[WOFF_BS2 + m + 16 * t];
  }
  float bs3f = w[WOFF_BS3];

  int T = (n_nodes + 15) >> 4;
  int wid = (int)((blockIdx.x * blockDim.x + threadIdx.x) >> 6);
  int nw = (int)((gridDim.x * blockDim.x) >> 6);
  f32x4 zero = {0.f, 0.f, 0.f, 0.f};

  for (int t0 = wid; t0 < T; t0 += nw) {
    long n0 = (long)t0 * 16;
    long row = n0 + m; if (row >= n_nodes) row = n_nodes - 1;
    bf16x8 a0 = afrag_row<BF16>(xv, row, 0);
    bf16x8 a1 = afrag_row<BF16>(xv, row, 32);
    f32x4 accp[2], accs[2];
#pragma unroll
    for (int t = 0; t < 2; t++) {
      accp[t] = __builtin_amdgcn_mfma_f32_16x16x32_bf16(a0, fwp[0][t], zero, 0, 0, 0);
      accp[t] = __builtin_amdgcn_mfma_f32_16x16x32_bf16(a1, fwp[1][t], accp[t], 0, 0, 0);
      accs[t] = __builtin_amdgcn_mfma_f32_16x16x32_bf16(a0, fws1[0][t], zero, 0, 0, 0);
      accs[t] = __builtin_amdgcn_mfma_f32_16x16x32_bf16(a1, fws1[1][t], accs[t], 0, 0, 0);
    }
    // xp = elu(pre): C-layout -> LDS bf16 -> row layout -> global
#pragma unroll
    for (int t = 0; t < 2; t++)
#pragma unroll
      for (int r = 0; r < 4; r++)
        buf[(quad * 4 + r) * 32 + m + 16 * t] = f2bu(eluf(accp[t][r] + bpv[t]));
    lds_fence();
    {
      uint4 rv = *(const uint4*)(buf + m * 32 + quad * 8);
      *(uint4*)(xp + row * 32 + quad * 8) = rv;
    }
    // s1 -> LDS -> A-frag
#pragma unroll
    for (int t = 0; t < 2; t++)
#pragma unroll
      for (int r = 0; r < 4; r++)
        buf[(quad * 4 + r) * 32 + m + 16 * t] = f2bu(eluf(accs[t][r] + bs1v[t]));
    lds_fence();
    U8 as1; as1.u = *(const uint4*)(buf + m * 32 + quad * 8);
    f32x4 acc2[2];
#pragma unroll
    for (int t = 0; t < 2; t++)
      acc2[t] = __builtin_amdgcn_mfma_f32_16x16x32_bf16(as1.v, fws2[t], zero, 0, 0, 0);
#pragma unroll
    for (int t = 0; t < 2; t++)
#pragma unroll
      for (int r = 0; r < 4; r++)
        buf[(quad * 4 + r) * 32 + m + 16 * t] = f2bu(eluf(acc2[t][r] + bs2v[t]));
    lds_fence();
    U8 as2; as2.u = *(const uint4*)(buf + m * 32 + quad * 8);
    f32x4 accx = __builtin_amdgcn_mfma_f32_16x16x32_bf16(as2.v, fws3, zero, 0, 0, 0);
    if (m == 0) {
#pragma unroll
      for (int r = 0; r < 4; r++) {
        long orow = n0 + quad * 4 + r;
        if (orow < n_nodes) xs[orow] = accx[r] + bs3f;
      }
    }
    lds_fence();  // protect buf before next iteration overwrites
  }
}

__launch_bounds__(256)
__global__ void preK(const void* xv, const float* __restrict__ w,
                     const int* __restrict__ flags,
                     ushort* __restrict__ xp, float* __restrict__ xs, int n_nodes) {
  __shared__ ushort sb[4 * 512];
  ushort* buf = sb + (threadIdx.x >> 6) * 512;
  if (flags[0]) pre_tiles<true>(xv, w, xp, xs, n_nodes, buf);
  else          pre_tiles<false>(xv, w, xp, xs, n_nodes, buf);
}

// ==================== kernel B: edge MLP + softmax (MFMA) ====================
template <bool BF16>
__device__ void edge_tiles(const ushort* __restrict__ xp, const float* __restrict__ xs,
                           const void* dsv, const int* __restrict__ ni, int i64,
                           const float* __restrict__ w, void* outv, int n_nodes,
                           ushort* buf, float* lbuf) {
  int lane = threadIdx.x & 63;
  int m = lane & 15, quad = lane >> 4;

  bf16x8 fsum[2], fwe1[KNB][2], fdsq[2], fwe2[2], fwe3;
#pragma unroll
  for (int t = 0; t < 2; t++) {
    fsum[t] = bfrag(w + WOFF_WSUM + 16 * t, 32, 16, 32, 1.f);
    fdsq[t] = bfrag(w + WOFF_WDSQ + 16 * t, 32, 16, KNB, 1.f);
    fwe2[t] = bfrag(w + WOFF_WE2 + 16 * t, 32, 16, 32, 1.f);
#pragma unroll
    for (int k = 0; k < KNB; k++)
      fwe1[k][t] = bfrag(w + WOFF_WE1 + k * 33 * 32 + 16 * t, 32, 16, 32, -1.f);
  }
  fwe3 = bfrag(w + WOFF_WE3, 6, 6, 32, 1.f);
  float be1v[2], be2v[2];
#pragma unroll
  for (int t = 0; t < 2; t++) {
    be1v[t] = w[WOFF_BE1 + m + 16 * t];
    be2v[t] = w[WOFF_BE2 + m + 16 * t];
  }
  float be3v = (m < 6) ? w[WOFF_BE3 + m] : 0.f;

  int T = (n_nodes + 15) >> 4;
  int wid = (int)((blockIdx.x * blockDim.x + threadIdx.x) >> 6);
  int nw = (int)((gridDim.x * blockDim.x) >> 6);
  f32x4 zero = {0.f, 0.f, 0.f, 0.f};

  for (int t0 = wid; t0 < T; t0 += nw) {
    long n0 = (long)t0 * 16;
    long row = n0 + m; if (row >= n_nodes) row = n_nodes - 1;

    int idxs[KNB];
#pragma unroll
    for (int k = 0; k < KNB; k++)
      idxs[k] = i64 ? ni[(row * KNB + k) * 2] : ni[row * KNB + k];

    U8 own; own.u = *(const uint4*)(xp + row * 32 + quad * 8);
    U8 nb[KNB];
#pragma unroll
    for (int k = 0; k < KNB; k++) {
      long ai = idxs[k];
      if (ai < 0 || ai >= n_nodes) ai = 0;
      nb[k].u = *(const uint4*)(xp + ai * 32 + quad * 8);
      if (idxs[k] < 0) { nb[k].u.x = 0; nb[k].u.y = 0; nb[k].u.z = 0; nb[k].u.w = 0; }
    }

    // dsq A-frag: A[m][k]=distsq[m][k] (k<6), rest 0; only quad 0 holds data
    U8 ad; ad.u.x = 0; ad.u.y = 0; ad.u.z = 0; ad.u.w = 0;
    if (quad == 0) {
      if (BF16) {
        const unsigned* dp = (const unsigned*)dsv;
        ad.u.x = dp[row * 3 + 0];
        ad.u.y = dp[row * 3 + 1];
        ad.u.z = dp[row * 3 + 2];
      } else {
        const float* dp = (const float*)dsv + row * KNB;
#pragma unroll
        for (int k = 0; k < KNB; k++) ad.s[k] = f2bu(dp[k]);
      }
    }

    // h1 = own@Wsum - sum_k nb_k@Wk + dsq@Wdsq  (two chains for ILP)
    f32x4 accA[2], accB[2];
#pragma unroll
    for (int t = 0; t < 2; t++) {
      accA[t] = __builtin_amdgcn_mfma_f32_16x16x32_bf16(own.v, fsum[t], zero, 0, 0, 0);
      accA[t] = __builtin_amdgcn_mfma_f32_16x16x32_bf16(nb[0].v, fwe1[0][t], accA[t], 0, 0, 0);
      accA[t] = __builtin_amdgcn_mfma_f32_16x16x32_bf16(nb[1].v, fwe1[1][t], accA[t], 0, 0, 0);
      accA[t] = __builtin_amdgcn_mfma_f32_16x16x32_bf16(nb[2].v, fwe1[2][t], accA[t], 0, 0, 0);
      accB[t] = __builtin_amdgcn_mfma_f32_16x16x32_bf16(nb[3].v, fwe1[3][t], zero, 0, 0, 0);
      accB[t] = __builtin_amdgcn_mfma_f32_16x16x32_bf16(nb[4].v, fwe1[4][t], accB[t], 0, 0, 0);
      accB[t] = __builtin_amdgcn_mfma_f32_16x16x32_bf16(nb[5].v, fwe1[5][t], accB[t], 0, 0, 0);
      accB[t] = __builtin_amdgcn_mfma_f32_16x16x32_bf16(ad.v, fdsq[t], accB[t], 0, 0, 0);
    }
    // elu -> LDS -> A-frag
#pragma unroll
    for (int t = 0; t < 2; t++)
#pragma unroll
      for (int r = 0; r < 4; r++)
        buf[(quad * 4 + r) * 32 + m + 16 * t] =
            f2bu(eluf(accA[t][r] + accB[t][r] + be1v[t]));
    lds_fence();
    U8 a1; a1.u = *(const uint4*)(buf + m * 32 + quad * 8);
    f32x4 acc2[2];
#pragma unroll
    for (int t = 0; t < 2; t++)
      acc2[t] = __builtin_amdgcn_mfma_f32_16x16x32_bf16(a1.v, fwe2[t], zero, 0, 0, 0);
#pragma unroll
    for (int t = 0; t < 2; t++)
#pragma unroll
      for (int r = 0; r < 4; r++)
        buf[(quad * 4 + r) * 32 + m + 16 * t] = f2bu(eluf(acc2[t][r] + be2v[t]));
    lds_fence();
    U8 a2; a2.u = *(const uint4*)(buf + m * 32 + quad * 8);
    f32x4 acc3 = __builtin_amdgcn_mfma_f32_16x16x32_bf16(a2.v, fwe3, zero, 0, 0, 0);

    if (m < 6) {
#pragma unroll
      for (int r = 0; r < 4; r++) lbuf[(quad * 4 + r) * 8 + m] = acc3[r] + be3v;
    }
    lds_fence();
    if (lane < 16) {
      long nodeid = n0 + lane;
      if (nodeid < n_nodes) {
        float lg[7];
        lg[0] = xs[nodeid];
#pragma unroll
        for (int i = 0; i < 6; i++) lg[1 + i] = lbuf[lane * 8 + i];
        float mx = lg[0];
#pragma unroll
        for (int i = 1; i < 7; i++) mx = fmaxf(mx, lg[i]);
        float e[7], ssum = 0.f;
#pragma unroll
        for (int i = 0; i < 7; i++) { e[i] = expf(lg[i] - mx); ssum += e[i]; }
        float inv = 1.f / ssum;
        if (BF16) {
          ushort* o = (ushort*)outv + nodeid * 7;
#pragma unroll
          for (int i = 0; i < 7; i++) o[i] = f2bu(e[i] * inv);
        } else {
          float* o = (float*)outv + nodeid * 7;
#pragma unroll
          for (int i = 0; i < 7; i++) o[i] = e[i] * inv;
        }
      }
    }
    lds_fence();  // protect lbuf/buf before next iteration
  }
}

__launch_bounds__(256)
__global__ void edgeK(const ushort* __restrict__ xp, const float* __restrict__ xs,
                      const void* dsv, const int* __restrict__ ni,
                      const float* __restrict__ w, const int* __restrict__ flags,
                      void* outv, int n_nodes) {
  __shared__ ushort sb[4 * 512];
  __shared__ float sl[4 * 128];
  ushort* buf = sb + (threadIdx.x >> 6) * 512;
  float* lbuf = sl + (threadIdx.x >> 6) * 128;
  int bf = flags[0];
  int i64 = flags[1];
  if (bf) edge_tiles<true>(xp, xs, dsv, ni, i64, w, outv, n_nodes, buf, lbuf);
  else    edge_tiles<false>(xp, xs, dsv, ni, i64, w, outv, n_nodes, buf, lbuf);
}

// ==================== fallback (proven round-2) path ====================
__device__ __forceinline__ void bf8_to_f32(uint4 u, float* f) {
  unsigned int w[4] = {u.x, u.y, u.z, u.w};
#pragma unroll
  for (int i = 0; i < 4; i++) {
    f[2 * i]     = __uint_as_float(w[i] << 16);
    f[2 * i + 1] = __uint_as_float(w[i] & 0xffff0000u);
  }
}

template <bool BF16>
__device__ __forceinline__ void load_row8(const void* base, long row, int chunk, float* f) {
  if (BF16) {
    const uint4* p = (const uint4*)((const ushort*)base + row * F_IN);
    bf8_to_f32(p[chunk], f);
  } else {
    const float4* p = (const float4*)((const float*)base + row * F_IN);
    float4 a = p[2 * chunk];
    float4 b = p[2 * chunk + 1];
    f[0] = a.x; f[1] = a.y; f[2] = a.z; f[3] = a.w;
    f[4] = b.x; f[5] = b.y; f[6] = b.z; f[7] = b.w;
  }
}

template <bool BF16>
__device__ void node_body(int n, int n_nodes, const void* xv, const void* dsv,
                          const int* __restrict__ ni, int i64,
                          const float* __restrict__ w, void* outv) {
  const float* Wp  = w + WOFF_WP;
  const float* bp  = w + WOFF_BP;
  const float* We1 = w + WOFF_WE1;
  const float* be1 = w + WOFF_BE1;
  const float* We2 = w + WOFF_WE2;
  const float* be2 = w + WOFF_BE2;
  const float* We3 = w + WOFF_WE3;
  const float* be3 = w + WOFF_BE3;
  const float* Ws1 = w + WOFF_WS1;
  const float* bs1 = w + WOFF_BS1;
  const float* Ws2 = w + WOFF_WS2;
  const float* bs2 = w + WOFF_BS2;
  const float* Ws3 = w + WOFF_WS3;
  const float* bs3 = w + WOFF_BS3;

  float h[32], s1[32];
#pragma unroll
  for (int o = 0; o < 32; o++) { h[o] = bp[o]; s1[o] = bs1[o]; }
  for (int c = 0; c < 8; c++) {
    float xv8[8];
    load_row8<BF16>(xv, n, c, xv8);
#pragma unroll
    for (int q = 0; q < 8; q++) {
      int j = c * 8 + q;
      float xj = xv8[q];
#pragma unroll
      for (int o = 0; o < 32; o++) {
        h[o]  += xj * Wp[j * 32 + o];
        s1[o] += xj * Ws1[j * 32 + o];
      }
    }
  }
  float own[32];
#pragma unroll
  for (int o = 0; o < 32; o++) own[o] = eluf(h[o]);
  float s2[32];
#pragma unroll
  for (int o = 0; o < 32; o++) s2[o] = bs2[o];
  for (int j = 0; j < 32; j++) {
    float v = eluf(s1[j]);
#pragma unroll
    for (int o = 0; o < 32; o++) s2[o] += v * Ws2[j * 32 + o];
  }
  float xsv = bs3[0];
#pragma unroll
  for (int j = 0; j < 32; j++) xsv += eluf(s2[j]) * Ws3[j];

  float h1[32];
#pragma unroll
  for (int o = 0; o < 32; o++) h1[o] = be1[o];
  for (int k = 0; k < KNB; k++) {
    long pos = (long)n * KNB + k;
    int idx = i64 ? ni[2 * pos] : ni[pos];
    float mmask = idx < 0 ? 0.f : 1.f;
    long ai = idx < 0 ? 0 : idx;
    if (ai >= n_nodes) ai = 0;
    float nh[32];
#pragma unroll
    for (int o = 0; o < 32; o++) nh[o] = bp[o];
    for (int c = 0; c < 8; c++) {
      float xv8[8];
      load_row8<BF16>(xv, ai, c, xv8);
#pragma unroll
      for (int q = 0; q < 8; q++) {
        int j = c * 8 + q;
        float xj = xv8[q];
#pragma unroll
        for (int o = 0; o < 32; o++) nh[o] += xj * Wp[j * 32 + o];
      }
    }
    const float* Wk = We1 + (k * 33) * 32;
#pragma unroll
    for (int j = 0; j < 32; j++) {
      float d = own[j] - mmask * eluf(nh[j]);
#pragma unroll
      for (int o = 0; o < 32; o++) h1[o] += d * Wk[j * 32 + o];
    }
    float dsq = BF16 ? b2f(((const bf16*)dsv)[pos]) : ((const float*)dsv)[pos];
#pragma unroll
    for (int o = 0; o < 32; o++) h1[o] += dsq * Wk[32 * 32 + o];
  }
  float h2[32];
#pragma unroll
  for (int o = 0; o < 32; o++) h2[o] = be2[o];
  for (int j = 0; j < 32; j++) {
    float v = eluf(h1[j]);
#pragma unroll
    for (int o = 0; o < 32; o++) h2[o] += v * We2[j * 32 + o];
  }
  float lg[7];
  lg[0] = xsv;
#pragma unroll
  for (int o = 0; o < 6; o++) lg[1 + o] = be3[o];
  for (int j = 0; j < 32; j++) {
    float v = eluf(h2[j]);
#pragma unroll
    for (int o = 0; o < 6; o++) lg[1 + o] += v * We3[j * 6 + o];
  }
  float mx = lg[0];
#pragma unroll
  for (int i = 1; i < 7; i++) mx = fmaxf(mx, lg[i]);
  float e[7], ssum = 0.f;
#pragma unroll
  for (int i = 0; i < 7; i++) { e[i] = expf(lg[i] - mx); ssum += e[i]; }
  float inv = 1.f / ssum;
  if (BF16) {
    bf16* o = (bf16*)outv;
#pragma unroll
    for (int i = 0; i < 7; i++) o[(long)n * 7 + i] = __float2bfloat16(e[i] * inv);
  } else {
    float* o = (float*)outv;
#pragma unroll
    for (int i = 0; i < 7; i++) o[(long)n * 7 + i] = e[i] * inv;
  }
}

__launch_bounds__(256)
__global__ void fused(const void* xv, const void* dsv, const int* __restrict__ ni,
                      const float* __restrict__ w, const int* __restrict__ flags,
                      void* outv, int n_nodes) {
  int n = blockIdx.x * blockDim.x + threadIdx.x;
  if (n >= n_nodes) return;
  int bf = flags[0];
  int i64 = flags[1];
  if (bf) node_body<true>(n, n_nodes, xv, dsv, ni, i64, w, outv);
  else    node_body<false>(n, n_nodes, xv, dsv, ni, i64, w, outv);
}

extern "C" void kernel_launch(void* const* d_in, const int* in_sizes, int n_in,
                              void* d_out, int out_size, void* d_ws, size_t ws_size,
                              hipStream_t stream) {
  const void* x      = d_in[0];
  const void* distsq = d_in[1];
  const int*  nidx   = (const int*)d_in[2];

  float* w = (float*)d_ws;
  int* flags = (int*)(w + FLAGS_OFF);
  int n_nodes = in_sizes[0] / F_IN;

  detect<<<1, 64, 0, stream>>>((const ushort*)x, nidx, flags);
  wstage<<<14, 256, 0, stream>>>(d_in[3], d_in[4], d_in[5], d_in[6], d_in[7], d_in[8],
                                 d_in[9], d_in[10], d_in[11], d_in[12], d_in[13], d_in[14],
                                 d_in[15], d_in[16], w, flags);
  wprep<<<4, 256, 0, stream>>>(w);

  size_t need = (size_t)STAGE_OFF * 4 + (size_t)n_nodes * 64 + (size_t)n_nodes * 4 + 256;
  if (ws_size >= need) {
    ushort* xp = (ushort*)(w + STAGE_OFF);
    float* xs = (float*)(xp + (size_t)n_nodes * 32);
    preK<<<1024, 256, 0, stream>>>(x, w, flags, xp, xs, n_nodes);
    edgeK<<<1024, 256, 0, stream>>>(xp, xs, distsq, nidx, w, flags, d_out, n_nodes);
  } else {
    int grid = (n_nodes + 255) / 256;
    fused<<<grid, 256, 0, stream>>>(x, distsq, nidx, w, flags, d_out, n_nodes);
  }
}